// Round 5
// baseline (398.728 us; speedup 1.0000x reference)
//
#include <hip/hip_runtime.h>
#include <cstdint>
#include <cstddef>

#define TT 1024
#define HH 1024
#define IW 1024
#define EE 16
#define KK 8
#define NSLOT (TT*KK)   // 8192
#define NTMAX 80        // max active (expert, mtile) pairs: 8192/128 + 16

typedef unsigned short u16;
typedef unsigned int   u32;
typedef __attribute__((ext_vector_type(4))) float f32x4;
typedef __attribute__((ext_vector_type(8))) short s16x8;
typedef __attribute__((ext_vector_type(8))) u16   u16x8;

// fp32 -> bf16 round-to-nearest-even (finite inputs only)
__device__ __forceinline__ u16 f2bf(float f) {
  union { float f; u32 u; } v; v.f = f;
  u32 u = v.u + 0x7fffu + ((v.u >> 16) & 1u);
  return (u16)(u >> 16);
}
__device__ __forceinline__ float bf2f(u16 b) {
  union { u32 u; float f; } v; v.u = (u32)b << 16;
  return v.f;
}

__device__ __forceinline__ void gload16(const void* g, void* l) {
  __builtin_amdgcn_global_load_lds(
      (const __attribute__((address_space(1))) u32*)g,
      (__attribute__((address_space(3))) u32*)l, 16, 0, 0);
}

#define MFMA16(a, b, c) __builtin_amdgcn_mfma_f32_16x16x32_bf16((a), (b), (c), 0, 0, 0)

// counted-vmcnt barrier: single asm so no memory op can slip between wait and barrier
#define WAITBAR(N) asm volatile("s_waitcnt vmcnt(" #N ")\n\ts_barrier" ::: "memory")

// ---------------- fused conversion: gate_up, down, x -> bf16 ----------------
// Fixed 2048-block grid; compile-time stride; unrolled chunks keep 8-16
// independent 16B loads in flight per thread (latency-bound fix, R4 counters).

#define CVT_BLOCKS 2048
#define CVT_STRIDE (CVT_BLOCKS * 256)

__device__ __forceinline__ void cvt8(const float* __restrict__ s, u16* __restrict__ d,
                                     size_t i) {
  const f32x4* p = (const f32x4*)(s + i * 8);
  f32x4 f0 = p[0], f1 = p[1];
  u16x8 o;
#pragma unroll
  for (int j = 0; j < 4; ++j) { o[j] = f2bf(f0[j]); o[j + 4] = f2bf(f1[j]); }
  *(u16x8*)(d + i * 8) = o;
}

__global__ void k_cvt_all(const float* __restrict__ hs, const float* __restrict__ gup,
                          const float* __restrict__ dp, u16* __restrict__ xb,
                          u16* __restrict__ gupb, u16* __restrict__ dpb) {
  const int g = blockIdx.x * 256 + threadIdx.x;
  // gup: 33.55M elems = 4194304 chunks = 8 strides
#pragma unroll
  for (int i = 0; i < 8; ++i) cvt8(gup, gupb, (size_t)g + (size_t)i * CVT_STRIDE);
  // dp: 16.78M elems = 2097152 chunks = 4 strides
#pragma unroll
  for (int i = 0; i < 4; ++i) cvt8(dp, dpb, (size_t)g + (size_t)i * CVT_STRIDE);
  // x: 1.05M elems = 131072 chunks
  if (g < 131072) cvt8(hs, xb, (size_t)g);
}

// ---------------- fused routing: count + scan + scatter + tile list, ONE block ----

__global__ void k_route(const int* __restrict__ idx, const float* __restrict__ tkw,
                        int* __restrict__ offsets, int* __restrict__ slot_token,
                        float* __restrict__ slot_w, int* __restrict__ inv,
                        int* __restrict__ tile_e, int* __restrict__ tile_mt) {
  __shared__ int cnt[EE], cur[EE];
  const int tid = threadIdx.x;
  if (tid < EE) cnt[tid] = 0;
  __syncthreads();
  for (int s = tid; s < NSLOT; s += 256) atomicAdd(&cnt[idx[s]], 1);
  __syncthreads();
  if (tid == 0) {
    int r = 0, t = 0;
    for (int e = 0; e < EE; ++e) {
      offsets[e] = r; cur[e] = r;
      int c = cnt[e];
      for (int mt = 0; mt * 128 < c; ++mt) { tile_e[t] = e; tile_mt[t] = mt; ++t; }
      r += c;
    }
    offsets[EE] = r;
    for (; t < NTMAX; ++t) tile_e[t] = -1;
  }
  __syncthreads();
  for (int s = tid; s < NSLOT; s += 256) {
    int e = idx[s];
    int pos = atomicAdd(&cur[e], 1);
    slot_token[pos] = s >> 3;   // token id (K=8)
    slot_w[pos] = tkw[s];
    inv[s] = pos;
  }
}

// ---------------- GEMM1: act = w * silu(X Wg^T) * (X Wu^T), per expert ----------------
// BM=128 slots, BN=64 channels (gate+up), BK=32, 4 waves (2x2).
// 3-buffer depth-2 pipeline, counted vmcnt(4), raw s_barrier (T3+T4).
// Swizzle: physical quarter p of row r holds source k-chunk p ^ ((r>>1)&3).

#define G1_ASZ (128*32)
#define G1_BSZ (64*32)
#define NK1 (HH/32)

__global__ __launch_bounds__(256, 3) void k_gemm1(
    const u16* __restrict__ xb,         // [T][H] bf16
    const u16* __restrict__ gupb,       // [E][2I][H] bf16
    const int* __restrict__ offsets,    // [E+1]
    const int* __restrict__ slot_token, // [NSLOT]
    const float* __restrict__ slot_w,   // [NSLOT]
    const int* __restrict__ tile_e,
    const int* __restrict__ tile_mt,
    u16* __restrict__ act)              // [NSLOT][I] bf16
{
  __shared__ __align__(16) u16 As[3 * G1_ASZ];   // 24 KiB
  __shared__ __align__(16) u16 Bgs[3 * G1_BSZ];  // 12 KiB
  __shared__ __align__(16) u16 Bus[3 * G1_BSZ];  // 12 KiB

  const int e = tile_e[blockIdx.y];
  if (e < 0) return;
  const int mt = tile_mt[blockIdx.y], nt = blockIdx.x;
  const int off = offsets[e];
  const int ne  = offsets[e + 1] - off;

  const int tid = threadIdx.x;
  const int lane = tid & 63, wid = tid >> 6;
  const int wm = wid >> 1, wn = wid & 1;

  // staging lane decomposition: 16 rows per gload16 call
  const int l4 = lane >> 2;                   // row within 16-row group
  const int lq = lane & 3;                    // physical quarter this lane fills
  const int chunk = lq ^ ((l4 >> 1) & 3);     // source k-chunk (write-side swizzle)

  const u16* asrc[2];
#pragma unroll
  for (int q = 0; q < 2; ++q) {
    int grow = mt * 128 + q * 64 + wid * 16 + l4;
    if (grow >= ne) grow = ne - 1;            // clamp: garbage rows never stored
    asrc[q] = xb + (size_t)slot_token[off + grow] * HH + chunk * 8;
  }
  const int bch = nt * 64 + wid * 16 + l4;    // output channel
  const u16* bgsrc = gupb + ((size_t)e * 2 * IW + bch) * HH + chunk * 8;
  const u16* busrc = bgsrc + (size_t)IW * HH;
  const int ad0 = (0 * 64 + wid * 16) * 32;
  const int ad1 = (1 * 64 + wid * 16) * 32;
  const int bd  = (wid * 16) * 32;

#define STAGE1(k0, buf)                                   \
  do {                                                    \
    gload16(asrc[0] + (k0), As  + (buf) * G1_ASZ + ad0);  \
    gload16(asrc[1] + (k0), As  + (buf) * G1_ASZ + ad1);  \
    gload16(bgsrc   + (k0), Bgs + (buf) * G1_BSZ + bd);   \
    gload16(busrc   + (k0), Bus + (buf) * G1_BSZ + bd);   \
  } while (0)

  f32x4 accg[4][2], accu[4][2];
  const f32x4 zz = {0.f, 0.f, 0.f, 0.f};
#pragma unroll
  for (int m = 0; m < 4; ++m)
#pragma unroll
    for (int n = 0; n < 2; ++n) { accg[m][n] = zz; accu[m][n] = zz; }

  const int r16 = lane & 15, kg = lane >> 4;
  const int rq = ((kg ^ ((r16 >> 1) & 3)) << 3);  // swizzled u16 offset of my k-chunk

  STAGE1(0, 0);
  STAGE1(32, 1);
  int cb = 0, pb = 2;
  for (int kk = 0; kk < NK1; ++kk) {
    if (kk + 1 < NK1) WAITBAR(4); else WAITBAR(0);  // tile kk landed (all waves)
    if (kk + 2 < NK1) STAGE1((kk + 2) * 32, pb);    // depth-2 prefetch
    const u16* Ab  = As  + cb * G1_ASZ;
    const u16* Bgb = Bgs + cb * G1_BSZ;
    const u16* Bub = Bus + cb * G1_BSZ;

    s16x8 a[4], bg[2], bu[2];
#pragma unroll
    for (int m = 0; m < 4; ++m)
      a[m] = *(const s16x8*)(Ab + (wm * 64 + m * 16 + r16) * 32 + rq);
#pragma unroll
    for (int n = 0; n < 2; ++n) {
      bg[n] = *(const s16x8*)(Bgb + (wn * 32 + n * 16 + r16) * 32 + rq);
      bu[n] = *(const s16x8*)(Bub + (wn * 32 + n * 16 + r16) * 32 + rq);
    }
#pragma unroll
    for (int m = 0; m < 4; ++m)
#pragma unroll
      for (int n = 0; n < 2; ++n) {
        accg[m][n] = MFMA16(a[m], bg[n], accg[m][n]);
        accu[m][n] = MFMA16(a[m], bu[n], accu[m][n]);
      }
    cb = (cb == 2) ? 0 : cb + 1;
    pb = (pb == 2) ? 0 : pb + 1;
  }
#undef STAGE1

  // epilogue: w * silu(g) * u -> bf16 act
#pragma unroll
  for (int m = 0; m < 4; ++m) {
    const int baserow = mt * 128 + wm * 64 + m * 16 + kg * 4;
#pragma unroll
    for (int n = 0; n < 2; ++n) {
      const int c = nt * 64 + wn * 32 + n * 16 + r16;
#pragma unroll
      for (int j = 0; j < 4; ++j) {
        const int row = baserow + j;
        if (row < ne) {
          float g = accg[m][n][j], u = accu[m][n][j];
          float sv = g / (1.f + __expf(-g));
          act[(size_t)(off + row) * IW + c] = f2bf(sv * u * slot_w[off + row]);
        }
      }
    }
  }
}

// ---------------- GEMM2: wdown = act @ down^T (bf16 out), per expert ----------------
// BM=128 slots, BN=128 h, BK=32, 4 waves (2x2), same pipeline.

#define G2_SZ (128*32)
#define NK2 (IW/32)

__global__ __launch_bounds__(256, 3) void k_gemm2(
    const u16* __restrict__ act,        // [NSLOT][I] bf16
    const u16* __restrict__ dpb,        // [E][H][I] bf16
    const int* __restrict__ offsets,
    const int* __restrict__ tile_e,
    const int* __restrict__ tile_mt,
    u16* __restrict__ wdown)            // [NSLOT][H] bf16
{
  __shared__ __align__(16) u16 As[3 * G2_SZ];  // 24 KiB
  __shared__ __align__(16) u16 Bs[3 * G2_SZ];  // 24 KiB

  const int e = tile_e[blockIdx.y];
  if (e < 0) return;
  const int mt = tile_mt[blockIdx.y], nt = blockIdx.x;
  const int off = offsets[e];
  const int ne  = offsets[e + 1] - off;

  const int tid = threadIdx.x;
  const int lane = tid & 63, wid = tid >> 6;
  const int wm = wid >> 1, wn = wid & 1;

  const int l4 = lane >> 2, lq = lane & 3;
  const int chunk = lq ^ ((l4 >> 1) & 3);

  const u16* asrc[2];
#pragma unroll
  for (int q = 0; q < 2; ++q) {
    int grow = mt * 128 + q * 64 + wid * 16 + l4;
    if (grow >= ne) grow = ne - 1;
    asrc[q] = act + (size_t)(off + grow) * IW + chunk * 8;
  }
  const u16* bsrc[2];
#pragma unroll
  for (int q = 0; q < 2; ++q)
    bsrc[q] = dpb + ((size_t)e * HH + nt * 128 + q * 64 + wid * 16 + l4) * IW + chunk * 8;

  const int d0 = (0 * 64 + wid * 16) * 32;
  const int d1 = (1 * 64 + wid * 16) * 32;

#define STAGE2(k0, buf)                                  \
  do {                                                   \
    gload16(asrc[0] + (k0), As + (buf) * G2_SZ + d0);    \
    gload16(asrc[1] + (k0), As + (buf) * G2_SZ + d1);    \
    gload16(bsrc[0] + (k0), Bs + (buf) * G2_SZ + d0);    \
    gload16(bsrc[1] + (k0), Bs + (buf) * G2_SZ + d1);    \
  } while (0)

  f32x4 acc[4][4];
  const f32x4 zz = {0.f, 0.f, 0.f, 0.f};
#pragma unroll
  for (int m = 0; m < 4; ++m)
#pragma unroll
    for (int n = 0; n < 4; ++n) acc[m][n] = zz;

  const int r16 = lane & 15, kg = lane >> 4;
  const int rq = ((kg ^ ((r16 >> 1) & 3)) << 3);

  STAGE2(0, 0);
  STAGE2(32, 1);
  int cb = 0, pb = 2;
  for (int kk = 0; kk < NK2; ++kk) {
    if (kk + 1 < NK2) WAITBAR(4); else WAITBAR(0);
    if (kk + 2 < NK2) STAGE2((kk + 2) * 32, pb);
    const u16* Ab = As + cb * G2_SZ;
    const u16* Bb = Bs + cb * G2_SZ;

    s16x8 a[4], b[4];
#pragma unroll
    for (int m = 0; m < 4; ++m)
      a[m] = *(const s16x8*)(Ab + (wm * 64 + m * 16 + r16) * 32 + rq);
#pragma unroll
    for (int n = 0; n < 4; ++n)
      b[n] = *(const s16x8*)(Bb + (wn * 64 + n * 16 + r16) * 32 + rq);
#pragma unroll
    for (int m = 0; m < 4; ++m)
#pragma unroll
      for (int n = 0; n < 4; ++n)
        acc[m][n] = MFMA16(a[m], b[n], acc[m][n]);
    cb = (cb == 2) ? 0 : cb + 1;
    pb = (pb == 2) ? 0 : pb + 1;
  }
#undef STAGE2

#pragma unroll
  for (int m = 0; m < 4; ++m) {
    const int baserow = mt * 128 + wm * 64 + m * 16 + kg * 4;
#pragma unroll
    for (int n = 0; n < 4; ++n) {
      const int h = nt * 128 + wn * 64 + n * 16 + r16;
#pragma unroll
      for (int j = 0; j < 4; ++j) {
        const int row = baserow + j;
        if (row < ne)
          wdown[(size_t)(off + row) * HH + h] = f2bf(acc[m][n][j]);
      }
    }
  }
}

// ---------------- combine: out[t,h] = sum_k wdown[inv[t,k]][h]  (w folded into act) ----

__global__ void k_combine(const u16* __restrict__ wdown, const int* __restrict__ inv,
                          float* __restrict__ out) {
  int g = blockIdx.x * 256 + threadIdx.x;   // T*H/8 threads
  int t = g >> 7;                           // 128 threads per token
  int hv = (g & 127) * 8;
  const int* ip = inv + t * KK;
  float acc[8] = {0.f, 0.f, 0.f, 0.f, 0.f, 0.f, 0.f, 0.f};
#pragma unroll
  for (int k = 0; k < KK; ++k) {
    int pos = ip[k];
    u16x8 v = *(const u16x8*)(wdown + (size_t)pos * HH + hv);
#pragma unroll
    for (int j = 0; j < 8; ++j) acc[j] += bf2f(v[j]);
  }
  f32x4 o0 = {acc[0], acc[1], acc[2], acc[3]};
  f32x4 o1 = {acc[4], acc[5], acc[6], acc[7]};
  *(f32x4*)(out + (size_t)t * HH + hv)     = o0;
  *(f32x4*)(out + (size_t)t * HH + hv + 4) = o1;
}

// ---------------- host ----------------

extern "C" void kernel_launch(void* const* d_in, const int* in_sizes, int n_in,
                              void* d_out, int out_size, void* d_ws, size_t ws_size,
                              hipStream_t stream) {
  const float* hs  = (const float*)d_in[0];
  const int*   idx = (const int*)d_in[1];
  const float* tkw = (const float*)d_in[2];
  const float* gup = (const float*)d_in[3];
  const float* dpw = (const float*)d_in[4];
  float* out = (float*)d_out;

  char* ws = (char*)d_ws;
  size_t o = 0;
  u16* xb   = (u16*)(ws + o);       o += (size_t)TT * HH * 2;            // 2 MiB
  u16* gupb = (u16*)(ws + o);       o += (size_t)EE * 2 * IW * HH * 2;   // 64 MiB
  u16* dpb  = (u16*)(ws + o);       o += (size_t)EE * HH * IW * 2;       // 32 MiB
  int* offsets = (int*)(ws + o);    o += 128;
  int* tile_e  = (int*)(ws + o);    o += NTMAX * 4;
  int* tile_mt = (int*)(ws + o);    o += NTMAX * 4;
  int* slot_token = (int*)(ws + o); o += (size_t)NSLOT * 4;
  int* inv     = (int*)(ws + o);    o += (size_t)NSLOT * 4;
  float* slot_w = (float*)(ws + o); o += (size_t)NSLOT * 4;
  o = (o + 255) & ~(size_t)255;
  u16* act = (u16*)(ws + o);        o += (size_t)NSLOT * IW * 2;         // 16 MiB
  u16* wdown = (u16*)(ws + o);      o += (size_t)NSLOT * HH * 2;         // 16 MiB
  // total ~130.5 MiB of ws

  k_route<<<1, 256, 0, stream>>>(idx, tkw, offsets, slot_token, slot_w, inv,
                                 tile_e, tile_mt);
  k_cvt_all<<<CVT_BLOCKS, 256, 0, stream>>>(hs, gup, dpw, xb, gupb, dpb);
  k_gemm1<<<dim3(IW / 64, NTMAX), 256, 0, stream>>>(xb, gupb, offsets, slot_token,
                                                    slot_w, tile_e, tile_mt, act);
  k_gemm2<<<dim3(HH / 128, NTMAX), 256, 0, stream>>>(act, dpb, offsets, tile_e,
                                                     tile_mt, wdown);
  k_combine<<<TT * HH / 8 / 256, 256, 0, stream>>>(wdown, inv, out);
}